// Round 10
// baseline (230.458 us; speedup 1.0000x reference)
//
#include <hip/hip_runtime.h>
#include <stdint.h>

typedef unsigned short u16;
typedef unsigned long long u64;
typedef __attribute__((ext_vector_type(8))) __bf16 bf16x8;
typedef __attribute__((ext_vector_type(4))) float f32x4;

#define Dn 512
#define Mn 16384  // T*B rows

// ---------- helpers ----------

__device__ __forceinline__ u16 f2bf(float f) {
  unsigned u = __float_as_uint(f);
  u += 0x7fffu + ((u >> 16) & 1u);
  return (u16)(u >> 16);
}

__device__ __forceinline__ float bf2f(u16 b) {
  return __uint_as_float(((unsigned)b) << 16);
}

__device__ __forceinline__ void async16(const u16* g, u16* l) {
  // global -> LDS direct copy, 16 B per lane. LDS dest = wave-uniform base + lane*16.
  __builtin_amdgcn_global_load_lds(
      (const __attribute__((address_space(1))) unsigned int*)g,
      (__attribute__((address_space(3))) unsigned int*)l, 16, 0, 0);
}

__device__ __forceinline__ float sigmoidf_(float v) {
  return 1.f / (1.f + __expf(-v));
}

// Agent-scope relaxed write-through stores: publish at the LLC so correctness is
// independent of workgroup->XCD mapping (G16). No buffer_inv/wbl2 (round-6 lesson:
// acquire-spin invalidation storms). Consumers use PLAIN loads (round-7 lesson:
// per-element coherent loads pay LLC latency): safe because every consumer line is
// first-touched AFTER the producer's flag within this kernel instance, and the
// dispatch-start acquire invalidates stale L1/L2 lines from previous replays
// (empirically validated by round 8 passing with this exact pattern).
__device__ __forceinline__ void st_u64_coh(u64* p, u64 v) {
  __hip_atomic_store(p, v, __ATOMIC_RELAXED, __HIP_MEMORY_SCOPE_AGENT);
}
__device__ __forceinline__ void st_u16_coh(u16* p, u16 v) {
  __hip_atomic_store(p, v, __ATOMIC_RELAXED, __HIP_MEMORY_SCOPE_AGENT);
}

__device__ __forceinline__ u64 pack4bf(float4 v) {
  u64 r = (u64)f2bf(v.x) | ((u64)f2bf(v.y) << 16) |
          ((u64)f2bf(v.z) << 32) | ((u64)f2bf(v.w) << 48);
  return r;
}

struct GArgs {
  const float *yf, *xf, *bg;
  const float *w0, *w1, *w2, *w3, *w4, *w5;
  u16 *yb, *xb, *rxb, *zb, *bRZ, *bG;
  float* out;
  unsigned *cflag, *rflag, *wcnt;  // cflag/rflag: 128 each (target 8); wcnt: 1 (target 128)
};

// ---------- single fused kernel (2 graph nodes total: memset + this) ----------
// Grid 1024 = 128 mb x 8 nb, nb FAST (mb = b>>3) so the 8 mb-siblings are CONTIGUOUS
// blockIdx -> co-dispatched at ANY occupancy (deadlock-safe; round-8's mb-fast layout
// silently required exactly-4-blocks/CU residency). Weights are cast by blocks 0..127.
// Grid 1024 = 4 blocks/CU with 32KB LDS (cap 5) and 60 VGPR -> ALL blocks co-resident
// regardless of dispatch order -> every spin satisfiable. All waits are relaxed
// loads + s_sleep with failsafe caps: worst case = wrong numerics, never a hang.
// Phases (bodies byte-match the round-8 passing kernel):
//   W (b<128): cast 6 weights -> bRZ/bG slices, write-through.        -> wcnt
//   A: cast 16 rows of y,x (rows mb*128+nb*16), write-through.        -> cflag[mb]
//   spin wcnt==128 && cflag[mb]==8
//   B: rz  C=[y|x]@bRZ^T, 128x128 tile; epilogue rx/z write-through.  -> rflag[mb]
//   C: gu half-0 (A=yb, no rz dep), 64x128 tile.
//   spin rflag[mb]==8
//   D: gu half-1 (A=rxb via plain async16); epilogue out=(1-z)x+z*tanh.
__global__ __launch_bounds__(256, 4) void fused_rzgu(GArgs a) {
  __shared__ u16 smem[16384];  // 32 KB: rz uses all, gu uses first 24 KB
  const int tid = (int)threadIdx.x;
  const int lane = tid & 63;
  const int wave = tid >> 6;
  const int waveM = wave >> 1, waveN = wave & 1;
  const int wbyte = (tid & 192) * 16;
  const int lm = lane & 15, quad = lane >> 4;
  const int srow = tid >> 3;
  const int scol = (((tid & 7) ^ ((tid >> 3) & 7)) * 8);
  const int lswz = lm & 7;
  const int b = (int)blockIdx.x;
  const int mb = b >> 3, nb = b & 7;  // nb fast -> siblings contiguous
  const int rowStart = mb * 128, colStart = nb * 128;

  // ================= phase W: weights cast (blocks 0..127 only) =================
  // 6 x 512x512 f32 -> bRZ (1024x1024 bf16: [Wr|Ur ; Wz|Uz]) and bG (512x1024: [Wg|Ug]).
  // 393216 float4 total = 128 blocks x 256 thr x 12. wi = i>>1 (uniform per iter).
  if (b < 128) {
#pragma unroll
    for (int i = 0; i < 12; ++i) {
      const int g = (b * 256 + tid) + i * 32768;
      const int wi = g >> 16;        // 0..5 : Wr,Ur,Wz,Uz,Wg,Ug
      const int i4 = g & 65535;      // float4 index within 512x512
      const float* src = wi == 0 ? a.w0 : wi == 1 ? a.w1 : wi == 2 ? a.w2
                       : wi == 3 ? a.w3 : wi == 4 ? a.w4 : a.w5;
      const int e  = i4 >> 7;        // output row 0..511
      const int c4 = i4 & 127;       // ushort4 col within 512
      const int row = e + ((wi == 2 || wi == 3) ? 512 : 0);
      const int off = row * 256 + c4 + ((wi & 1) ? 128 : 0);
      u64* base = (wi >= 4) ? (u64*)a.bG : (u64*)a.bRZ;
      st_u64_coh(base + off, pack4bf(((const float4*)src)[i4]));
    }
  }

  // ================= phase A: cast 16 rows of y and x =================
  {
    const int r0 = rowStart + nb * 16;
#pragma unroll
    for (int k = tid; k < 2048; k += 256) {
      const int gi = (r0 + (k >> 7)) * 128 + (k & 127);
      st_u64_coh((u64*)a.yb + gi, pack4bf(((const float4*)a.yf)[gi]));
      st_u64_coh((u64*)a.xb + gi, pack4bf(((const float4*)a.xf)[gi]));
    }
  }
  asm volatile("s_waitcnt vmcnt(0)" ::: "memory");
  __syncthreads();
  if (tid == 0) {
    if (b < 128)
      __hip_atomic_fetch_add(a.wcnt, 1u, __ATOMIC_RELAXED, __HIP_MEMORY_SCOPE_AGENT);
    __hip_atomic_fetch_add(&a.cflag[mb], 1u, __ATOMIC_RELAXED, __HIP_MEMORY_SCOPE_AGENT);
    unsigned spins = 0;
    while (__hip_atomic_load(a.wcnt, __ATOMIC_RELAXED, __HIP_MEMORY_SCOPE_AGENT) < 128u) {
      __builtin_amdgcn_s_sleep(4);
      if (++spins > (1u << 20)) break;  // failsafe
    }
    spins = 0;
    while (__hip_atomic_load(&a.cflag[mb], __ATOMIC_RELAXED, __HIP_MEMORY_SCOPE_AGENT) < 8u) {
      __builtin_amdgcn_s_sleep(4);
      if (++spins > (1u << 20)) break;  // failsafe
    }
  }
  __syncthreads();
  __builtin_amdgcn_sched_barrier(0);

  // ================= phase B: rz  C=[y|x]@bRZ^T, 128x128 tile =================
  {
    u16* sA = smem;
    u16* sB = smem + 8192;

    f32x4 acc[4][4] = {};

    for (int kq = 0; kq < 16; ++kq) {
      const int half = kq >> 3;
      const int k0 = (kq & 7) * 64;
      const u16* abase = half ? a.xb : a.yb;  // A = [y | x] along K
#pragma unroll
      for (int s = 0; s < 4; ++s) {
        async16(abase + (size_t)(rowStart + s * 32 + srow) * 512 + k0 + scol,
                (u16*)((char*)sA + s * 4096 + wbyte));
        async16(a.bRZ + (size_t)(colStart + s * 32 + srow) * 1024 + kq * 64 + scol,
                (u16*)((char*)sB + s * 4096 + wbyte));
      }
      __syncthreads();

#pragma unroll
      for (int kk = 0; kk < 2; ++kk) {
        bf16x8 aa[4], bw[4];
#pragma unroll
        for (int i = 0; i < 4; ++i)
          aa[i] = *(const bf16x8*)(sA + (waveM * 64 + i * 16 + lm) * 64 +
                                   ((kk * 4 + quad) ^ lswz) * 8);
#pragma unroll
        for (int j = 0; j < 4; ++j)
          bw[j] = *(const bf16x8*)(sB + (waveN * 64 + j * 16 + lm) * 64 +
                                   ((kk * 4 + quad) ^ lswz) * 8);
#pragma unroll
        for (int i = 0; i < 4; ++i)
#pragma unroll
          for (int j = 0; j < 4; ++j)
            acc[i][j] = __builtin_amdgcn_mfma_f32_16x16x32_bf16(aa[i], bw[j], acc[i][j], 0, 0, 0);
      }
      __syncthreads();
    }

    if (colStart < 512) {
      // R half: rx = bf16(sigmoid(acc) * x), write-through
#pragma unroll
      for (int j = 0; j < 4; ++j) {
        const int e = colStart + waveN * 64 + j * 16 + lm;
#pragma unroll
        for (int i = 0; i < 4; ++i) {
          const int m0 = rowStart + waveM * 64 + i * 16 + quad * 4;
#pragma unroll
          for (int rg = 0; rg < 4; ++rg) {
            const size_t idx = (size_t)(m0 + rg) * 512 + e;
            const float r = sigmoidf_(acc[i][j][rg]);
            st_u16_coh(&a.rxb[idx], f2bf(r * bf2f(a.xb[idx])));
          }
        }
      }
    } else {
      // Z half: z = bf16(sigmoid(acc - bg)), write-through
#pragma unroll
      for (int j = 0; j < 4; ++j) {
        const int e = colStart - 512 + waveN * 64 + j * 16 + lm;
        const float bgv = a.bg[e];
#pragma unroll
        for (int i = 0; i < 4; ++i) {
          const int m0 = rowStart + waveM * 64 + i * 16 + quad * 4;
#pragma unroll
          for (int rg = 0; rg < 4; ++rg) {
            const size_t idx = (size_t)(m0 + rg) * 512 + e;
            st_u16_coh(&a.zb[idx], f2bf(sigmoidf_(acc[i][j][rg] - bgv)));
          }
        }
      }
    }
  }
  asm volatile("s_waitcnt vmcnt(0)" ::: "memory");
  __syncthreads();
  if (tid == 0)
    __hip_atomic_fetch_add(&a.rflag[mb], 1u, __ATOMIC_RELAXED, __HIP_MEMORY_SCOPE_AGENT);

  // ================= phase C/D: gu  accF=[y|rx]@bG^T, 64x128 tile =================
  {
    u16* sA = smem;          // 2 slabs x 4 KB
    u16* sB = smem + 4096;   // 4 slabs x 4 KB
    const int rowG = rowStart + (nb & 1) * 64;
    const int colG = (nb >> 1) * 128;

    f32x4 acc[2][4] = {};

    // ---- K-half 0: A = yb (cast-complete; no rz dependency) ----
    for (int kq = 0; kq < 8; ++kq) {
      const int k0 = kq * 64;
#pragma unroll
      for (int s = 0; s < 2; ++s)
        async16(a.yb + (size_t)(rowG + s * 32 + srow) * 512 + k0 + scol,
                (u16*)((char*)sA + s * 4096 + wbyte));
#pragma unroll
      for (int s = 0; s < 4; ++s)
        async16(a.bG + (size_t)(colG + s * 32 + srow) * 1024 + kq * 64 + scol,
                (u16*)((char*)sB + s * 4096 + wbyte));
      __syncthreads();

#pragma unroll
      for (int kk = 0; kk < 2; ++kk) {
        bf16x8 aa[2], bw[4];
#pragma unroll
        for (int i = 0; i < 2; ++i)
          aa[i] = *(const bf16x8*)(sA + (waveM * 32 + i * 16 + lm) * 64 +
                                   ((kk * 4 + quad) ^ lswz) * 8);
#pragma unroll
        for (int j = 0; j < 4; ++j)
          bw[j] = *(const bf16x8*)(sB + (waveN * 64 + j * 16 + lm) * 64 +
                                   ((kk * 4 + quad) ^ lswz) * 8);
#pragma unroll
        for (int i = 0; i < 2; ++i)
#pragma unroll
          for (int j = 0; j < 4; ++j)
            acc[i][j] = __builtin_amdgcn_mfma_f32_16x16x32_bf16(aa[i], bw[j], acc[i][j], 0, 0, 0);
      }
      __syncthreads();
    }

    // ---- wait for the 8 mb-sibling rz blocks (contiguous blockIdx -> always resident) ----
    if (tid == 0) {
      unsigned spins = 0;
      while (__hip_atomic_load(&a.rflag[mb], __ATOMIC_RELAXED, __HIP_MEMORY_SCOPE_AGENT) < 8u) {
        __builtin_amdgcn_s_sleep(4);
        if (++spins > (1u << 20)) break;  // failsafe
      }
    }
    __syncthreads();
    __builtin_amdgcn_sched_barrier(0);

    // ---- K-half 1: A = rxb via PLAIN global_load_lds (first touch after flag) ----
    for (int kq = 8; kq < 16; ++kq) {
      const int k0 = (kq & 7) * 64;
#pragma unroll
      for (int s = 0; s < 2; ++s)
        async16(a.rxb + (size_t)(rowG + s * 32 + srow) * 512 + k0 + scol,
                (u16*)((char*)sA + s * 4096 + wbyte));
#pragma unroll
      for (int s = 0; s < 4; ++s)
        async16(a.bG + (size_t)(colG + s * 32 + srow) * 1024 + kq * 64 + scol,
                (u16*)((char*)sB + s * 4096 + wbyte));
      __syncthreads();

#pragma unroll
      for (int kk = 0; kk < 2; ++kk) {
        bf16x8 aa[2], bw[4];
#pragma unroll
        for (int i = 0; i < 2; ++i)
          aa[i] = *(const bf16x8*)(sA + (waveM * 32 + i * 16 + lm) * 64 +
                                   ((kk * 4 + quad) ^ lswz) * 8);
#pragma unroll
        for (int j = 0; j < 4; ++j)
          bw[j] = *(const bf16x8*)(sB + (waveN * 64 + j * 16 + lm) * 64 +
                                   ((kk * 4 + quad) ^ lswz) * 8);
#pragma unroll
        for (int i = 0; i < 2; ++i)
#pragma unroll
          for (int j = 0; j < 4; ++j)
            acc[i][j] = __builtin_amdgcn_mfma_f32_16x16x32_bf16(aa[i], bw[j], acc[i][j], 0, 0, 0);
      }
      __syncthreads();
    }

    // epilogue: out = (1-z)x + z*tanh(accF); zb/xb PLAIN loads
#pragma unroll
    for (int j = 0; j < 4; ++j) {
      const int e = colG + waveN * 64 + j * 16 + lm;
#pragma unroll
      for (int i = 0; i < 2; ++i) {
        const int m0 = rowG + waveM * 32 + i * 16 + quad * 4;
#pragma unroll
        for (int rg = 0; rg < 4; ++rg) {
          const size_t idx = (size_t)(m0 + rg) * 512 + e;
          const float pre = acc[i][j][rg];
          const float ex = __expf(-2.f * pre);
          const float h = (1.f - ex) / (1.f + ex);  // tanh
          const float z = bf2f(a.zb[idx]);
          const float xv = bf2f(a.xb[idx]);
          a.out[idx] = (1.f - z) * xv + z * h;
        }
      }
    }
  }
}

// ---------- launch ----------
extern "C" void kernel_launch(void* const* d_in, const int* in_sizes, int n_in,
                              void* d_out, int out_size, void* d_ws, size_t ws_size,
                              hipStream_t stream) {
  // ws layout (bytes): yb 16M | xb 16M | rxb 16M | zb 16M | bRZ 2M | bG 1M | flags 2K
  char* ws = (char*)d_ws;
  u16* yb  = (u16*)(ws);
  u16* xb  = (u16*)(ws + 16777216);
  u16* rxb = (u16*)(ws + 2 * 16777216);
  u16* zb  = (u16*)(ws + 3 * 16777216);
  u16* bRZ = (u16*)(ws + 4 * 16777216);
  u16* bG  = (u16*)(ws + 4 * 16777216 + 2097152);
  char* flags = ws + 4 * 16777216 + 2097152 + 1048576;

  GArgs ga;
  ga.yf = (const float*)d_in[1];  // y
  ga.xf = (const float*)d_in[0];  // x
  ga.bg = (const float*)d_in[8];
  ga.w0 = (const float*)d_in[2];  // Wr
  ga.w1 = (const float*)d_in[3];  // Ur
  ga.w2 = (const float*)d_in[4];  // Wz
  ga.w3 = (const float*)d_in[5];  // Uz
  ga.w4 = (const float*)d_in[6];  // Wg
  ga.w5 = (const float*)d_in[7];  // Ug
  ga.yb = yb; ga.xb = xb; ga.rxb = rxb; ga.zb = zb;
  ga.bRZ = bRZ; ga.bG = bG;
  ga.out = (float*)d_out;
  ga.cflag = (unsigned*)flags;
  ga.rflag = (unsigned*)(flags + 512);
  ga.wcnt  = (unsigned*)(flags + 1024);

  // Captured into the graph -> flags re-zeroed on every replay.
  hipMemsetAsync(flags, 0, 2048, stream);
  fused_rzgu<<<1024, 256, 0, stream>>>(ga);
}